// Round 6
// baseline (307.507 us; speedup 1.0000x reference)
//
#include <hip/hip_runtime.h>
#include <hip/hip_cooperative_groups.h>

namespace cg = cooperative_groups;

#define T 256
#define H 512
#define EPSF 1e-5f

__device__ __forceinline__ float block_sum(float v, float* s4) {
    for (int o = 32; o; o >>= 1) v += __shfl_xor(v, o);
    int w = threadIdx.x >> 6;
    __syncthreads();
    if ((threadIdx.x & 63) == 0) s4[w] = v;
    __syncthreads();
    return s4[0] + s4[1] + s4[2] + s4[3];
}

__device__ __forceinline__ float block_max(float v, float* s4) {
    for (int o = 32; o; o >>= 1) v = fmaxf(v, __shfl_xor(v, o));
    int w = threadIdx.x >> 6;
    __syncthreads();
    if ((threadIdx.x & 63) == 0) s4[w] = v;
    __syncthreads();
    return fmaxf(fmaxf(s4[0], s4[1]), fmaxf(s4[2], s4[3]));
}

// ---- Phase 1a: S-scan (8 units), 64 cols/unit, wave = 64-t chunk ----
__device__ void p1_scan(int un, const float* __restrict__ h,
                        float* __restrict__ S, float* smem) {
    float (*csum)[64] = (float (*)[64])smem;
    int tid = threadIdx.x, lane = tid & 63, w = tid >> 6;
    int q = un * 64 + lane;
    int tbase = w * 64;
    float s = 0.f;
    for (int j = 0; j < 64; j += 8) {
        float v[8];
        #pragma unroll
        for (int u = 0; u < 8; ++u) v[u] = h[(tbase + j + u) * H + q];
        #pragma unroll
        for (int u = 0; u < 8; ++u) s += v[u];
    }
    csum[w][lane] = s;
    __syncthreads();
    float acc = 0.f;
    #pragma unroll
    for (int w2 = 0; w2 < 3; ++w2) if (w2 < w) acc += csum[w2][lane];
    for (int j = 0; j < 64; j += 8) {
        float v[8];
        #pragma unroll
        for (int u = 0; u < 8; ++u) v[u] = h[(tbase + j + u) * H + q];
        #pragma unroll
        for (int u = 0; u < 8; ++u) { acc += v[u]; S[(tbase + j + u) * H + q] = acc; }
    }
}

// ---- Phase 1b: Z=relu(h@U+a), HZ=h.*Z, c.  Tile 8t x 64q, FULL-K/thread ----
__device__ void p1_gemm8(int u, const float* __restrict__ h, const float* __restrict__ U,
                         const float* __restrict__ a, float* __restrict__ Z,
                         float* __restrict__ HZ, float* __restrict__ c, float* smem) {
    int tid = threadIdx.x;
    int t0 = (u >> 3) * 8;
    int qc0 = (u & 7) * 32;
    float* sh = smem;                         // 8 rows x 512 = 16 KB
    #pragma unroll
    for (int j = 0; j < 4; ++j)
        ((float4*)sh)[tid + j * 256] = ((const float4*)(h + t0 * H))[tid + j * 256];
    __syncthreads();

    if ((u & 7) == 0) {                       // c for the 8 staged rows
        int w = tid >> 6, lane = tid & 63;
        int row = 2 * w + (lane >> 5), l5 = lane & 31;
        float s = 0.f;
        #pragma unroll
        for (int j = 0; j < 16; ++j) s += sh[row * 512 + l5 + j * 32];
        #pragma unroll
        for (int o = 16; o; o >>= 1) s += __shfl_xor(s, o);
        if (l5 == 0) c[t0 + row] = s;
    }

    int r = tid >> 5;
    int qc = qc0 + (tid & 31);
    const float2* U2 = (const float2*)U;
    float2 ac0 = {0.f, 0.f}, ac1 = {0.f, 0.f}, ac2 = {0.f, 0.f}, ac3 = {0.f, 0.f};
    for (int k0 = 0; k0 < 512; k0 += 8) {
        float2 uv[8]; float av[8];
        #pragma unroll
        for (int j = 0; j < 8; ++j) uv[j] = U2[(k0 + j) * 256 + qc];
        #pragma unroll
        for (int j = 0; j < 8; ++j) av[j] = sh[r * 512 + k0 + j];
        ac0.x += av[0] * uv[0].x; ac0.y += av[0] * uv[0].y;
        ac1.x += av[1] * uv[1].x; ac1.y += av[1] * uv[1].y;
        ac2.x += av[2] * uv[2].x; ac2.y += av[2] * uv[2].y;
        ac3.x += av[3] * uv[3].x; ac3.y += av[3] * uv[3].y;
        ac0.x += av[4] * uv[4].x; ac0.y += av[4] * uv[4].y;
        ac1.x += av[5] * uv[5].x; ac1.y += av[5] * uv[5].y;
        ac2.x += av[6] * uv[6].x; ac2.y += av[6] * uv[6].y;
        ac3.x += av[7] * uv[7].x; ac3.y += av[7] * uv[7].y;
    }
    float2 acc;
    acc.x = (ac0.x + ac1.x) + (ac2.x + ac3.x);
    acc.y = (ac0.y + ac1.y) + (ac2.y + ac3.y);
    float2 av2 = ((const float2*)a)[qc];
    float zx = fmaxf(acc.x + av2.x, 0.f), zy = fmaxf(acc.y + av2.y, 0.f);
    float2 hv = ((const float2*)sh)[r * 256 + qc];
    ((float2*)Z)[(t0 + r) * 256 + qc]  = make_float2(zx, zy);
    ((float2*)HZ)[(t0 + r) * 256 + qc] = make_float2(hv.x * zx, hv.y * zy);
}

// ---- Phase 2a: u0 = Z@W + b, same 8t x 64q full-K tiling, u in [0,256) ----
__device__ void p2_gemm8(int u, const float* __restrict__ Z, const float* __restrict__ W,
                         const float* __restrict__ bb, float* __restrict__ u0,
                         float* smem) {
    int tid = threadIdx.x;
    int t0 = (u >> 3) * 8;
    int qc0 = (u & 7) * 32;
    float* sh = smem;
    #pragma unroll
    for (int j = 0; j < 4; ++j)
        ((float4*)sh)[tid + j * 256] = ((const float4*)(Z + t0 * H))[tid + j * 256];
    __syncthreads();

    int r = tid >> 5;
    int qc = qc0 + (tid & 31);
    const float2* W2 = (const float2*)W;
    float2 ac0 = {0.f, 0.f}, ac1 = {0.f, 0.f}, ac2 = {0.f, 0.f}, ac3 = {0.f, 0.f};
    for (int k0 = 0; k0 < 512; k0 += 8) {
        float2 wv[8]; float av[8];
        #pragma unroll
        for (int j = 0; j < 8; ++j) wv[j] = W2[(k0 + j) * 256 + qc];
        #pragma unroll
        for (int j = 0; j < 8; ++j) av[j] = sh[r * 512 + k0 + j];
        ac0.x += av[0] * wv[0].x; ac0.y += av[0] * wv[0].y;
        ac1.x += av[1] * wv[1].x; ac1.y += av[1] * wv[1].y;
        ac2.x += av[2] * wv[2].x; ac2.y += av[2] * wv[2].y;
        ac3.x += av[3] * wv[3].x; ac3.y += av[3] * wv[3].y;
        ac0.x += av[4] * wv[4].x; ac0.y += av[4] * wv[4].y;
        ac1.x += av[5] * wv[5].x; ac1.y += av[5] * wv[5].y;
        ac2.x += av[6] * wv[6].x; ac2.y += av[6] * wv[6].y;
        ac3.x += av[7] * wv[7].x; ac3.y += av[7] * wv[7].y;
    }
    float2 acc;
    acc.x = (ac0.x + ac1.x) + (ac2.x + ac3.x);
    acc.y = (ac0.y + ac1.y) + (ac2.y + ac3.y);
    float2 bv = ((const float2*)bb)[qc];
    ((float2*)u0)[(t0 + r) * 256 + qc] = make_float2(acc.x + bv.x, acc.y + bv.y);
}

// ---- Phase 2b: Beta = tril(Z@HZ^T,-1)+c, compact triangular 8x8 tile e in [0,528) ----
__device__ void p2_beta(int e, const float* __restrict__ Z, const float* __restrict__ HZ,
                        const float* __restrict__ c, float* __restrict__ Beta,
                        float* smem) {
    int tid = threadIdx.x;
    int ti = (int)((sqrtf(8.f * (float)e + 1.f) - 1.f) * 0.5f);
    while ((ti + 1) * (ti + 2) / 2 <= e) ++ti;
    while (ti * (ti + 1) / 2 > e) --ti;
    int ii = e - ti * (ti + 1) / 2;
    int t0 = ti * 8, i0 = ii * 8;
    float* Zs = smem;                  // [8][516]
    float* Hs = smem + 8 * 516;        // [8][516]
    float* red = smem + 2 * 8 * 516;   // [4][64]
    #pragma unroll
    for (int j = 0; j < 4; ++j) {
        int idx = tid + j * 256;
        int row = idx >> 7, col4 = idx & 127;
        float4 v = ((const float4*)(Z + (t0 + row) * H))[col4];
        *(float4*)&Zs[row * 516 + col4 * 4] = v;
        float4 g = ((const float4*)(HZ + (i0 + row) * H))[col4];
        *(float4*)&Hs[row * 516 + col4 * 4] = g;
    }
    __syncthreads();
    int ks = tid >> 6, r = (tid >> 3) & 7, ci = tid & 7;
    float acc = 0.f;
    int kb = ks * 128;
    #pragma unroll 4
    for (int k0 = kb; k0 < kb + 128; k0 += 8) {
        float4 z0 = *(float4*)&Zs[r * 516 + k0];
        float4 z1 = *(float4*)&Zs[r * 516 + k0 + 4];
        float4 h0 = *(float4*)&Hs[ci * 516 + k0];
        float4 h1 = *(float4*)&Hs[ci * 516 + k0 + 4];
        acc += z0.x * h0.x + z0.y * h0.y + z0.z * h0.z + z0.w * h0.w
             + z1.x * h1.x + z1.y * h1.y + z1.z * h1.z + z1.w * h1.w;
    }
    red[ks * 64 + r * 8 + ci] = acc;
    __syncthreads();
    if (tid < 64) {
        int r2 = tid >> 3, c2 = tid & 7;
        float v = red[tid] + red[64 + tid] + red[128 + tid] + red[192 + tid];
        int t = t0 + r2, i = i0 + c2;
        Beta[t * 256 + i] = (i < t) ? v + c[i] : 0.f;
    }
}

// ---- Phase 3: per-row LN -> softmax grad -> LN-backward -> D, SD ----
__device__ void p3_row(int t, const float* __restrict__ u0, const float* __restrict__ gamma,
                       const float* __restrict__ beta, const int* __restrict__ targets,
                       const float* __restrict__ S, float* __restrict__ D,
                       float* __restrict__ SD, float* smem) {
    float* s4 = smem;
    int tid = threadIdx.x;
    float2 uv = ((const float2*)u0)[t * 256 + tid];
    float2 gv = ((const float2*)gamma)[tid];
    float2 bv = ((const float2*)beta)[tid];

    float m = block_sum(uv.x + uv.y, s4) * (1.f / H);
    float d0 = uv.x - m, d1 = uv.y - m;
    float var = block_sum(d0 * d0 + d1 * d1, s4) * (1.f / H);
    float s = rsqrtf(var + EPSF);
    float xh0 = d0 * s, xh1 = d1 * s;
    float y0 = xh0 * gv.x + bv.x;
    float y1 = xh1 * gv.y + bv.y;

    float ymax = block_max(fmaxf(y0, y1), s4);
    float e0 = __expf(y0 - ymax), e1 = __expf(y1 - ymax);
    float Zs = block_sum(e0 + e1, s4);
    float invZ = 1.f / Zs;
    int tgt = targets[t];
    float g0 = e0 * invZ - (2 * tid == tgt ? 1.f : 0.f);
    float g1 = e1 * invZ - (2 * tid + 1 == tgt ? 1.f : 0.f);
    float gy0 = g0 * gv.x, gy1 = g1 * gv.y;

    float mgy = block_sum(gy0 + gy1, s4) * (1.f / H);
    float mgx = block_sum(gy0 * xh0 + gy1 * xh1, s4) * (1.f / H);

    float dd0 = s * (gy0 - mgy - xh0 * mgx);
    float dd1 = s * (gy1 - mgy - xh1 * mgx);
    float2 sv = ((const float2*)S)[t * 256 + tid];
    ((float2*)D)[t * 256 + tid]  = make_float2(dd0, dd1);
    ((float2*)SD)[t * 256 + tid] = make_float2(sv.x * dd0, sv.y * dd1);
}

// ---- Phase 4: per-row A1=Beta_t@D, A2=Beta_t@SD; pre = u0 - S.*A1 + A2; LN ----
__device__ void p4_row(int t, const float* __restrict__ Beta, const float* __restrict__ D,
                       const float* __restrict__ SD, const float* __restrict__ u0,
                       const float* __restrict__ S, const float* __restrict__ gamma,
                       const float* __restrict__ beta, float* __restrict__ out,
                       float* smem) {
    float* Brow = smem;          // 256
    float* s4 = smem + 256;      // 4
    int tid = threadIdx.x;
    Brow[tid] = Beta[t * 256 + tid];
    __syncthreads();

    int tcap = min(256, (t + 7) & ~7);    // Beta zero-padded to tile boundary
    float2 a1 = {0.f, 0.f}, a2 = {0.f, 0.f};
    const float2* D2 = (const float2*)D;
    const float2* SD2 = (const float2*)SD;
    for (int k0 = 0; k0 < tcap; k0 += 8) {
        float2 dv[8], sv[8];
        #pragma unroll
        for (int u = 0; u < 8; ++u) {
            dv[u] = D2[(k0 + u) * 256 + tid];
            sv[u] = SD2[(k0 + u) * 256 + tid];
        }
        #pragma unroll
        for (int u = 0; u < 8; ++u) {
            float bw = Brow[k0 + u];
            a1.x += bw * dv[u].x; a1.y += bw * dv[u].y;
            a2.x += bw * sv[u].x; a2.y += bw * sv[u].y;
        }
    }
    float2 uv = ((const float2*)u0)[t * 256 + tid];
    float2 sv2 = ((const float2*)S)[t * 256 + tid];
    float p0 = uv.x - sv2.x * a1.x + a2.x;
    float p1 = uv.y - sv2.y * a1.y + a2.y;

    float m = block_sum(p0 + p1, s4) * (1.f / H);
    float d0 = p0 - m, d1 = p1 - m;
    float var = block_sum(d0 * d0 + d1 * d1, s4) * (1.f / H);
    float s = rsqrtf(var + EPSF);
    float2 gv = ((const float2*)gamma)[tid];
    float2 bv = ((const float2*)beta)[tid];
    ((float2*)out)[t * 256 + tid] =
        make_float2(d0 * s * gv.x + bv.x, d1 * s * gv.y + bv.y);
}

// ---- Fused cooperative kernel: 520 blocks x 256 threads, 3 grid barriers ----
__global__ __launch_bounds__(256, 3) void fused(
        const float* __restrict__ h, const float* __restrict__ U,
        const float* __restrict__ W, const float* __restrict__ a,
        const float* __restrict__ bb, const float* __restrict__ gamma,
        const float* __restrict__ beta, const int* __restrict__ targets,
        float* __restrict__ Z, float* __restrict__ HZ, float* __restrict__ c,
        float* __restrict__ S, float* __restrict__ u0, float* __restrict__ D,
        float* __restrict__ SD, float* __restrict__ Beta, float* __restrict__ out) {
    __shared__ __align__(16) float smem[2 * 8 * 516 + 256];   // 8512 floats = 34 KB
    cg::grid_group grid = cg::this_grid();
    int bid = blockIdx.x;

    // Phase 1: Z/HZ/c GEMM (256 units) + S-scan (8 units)
    if (bid < 256)      p1_gemm8(bid, h, U, a, Z, HZ, c, smem);
    else if (bid < 264) p1_scan(bid - 256, h, S, smem);
    grid.sync();

    // Phase 2: u0 GEMM (256 units) + all 528 Beta tiles (264 blocks x 2)
    if (bid < 256) {
        p2_gemm8(bid, Z, W, bb, u0, smem);
    } else {
        int e0 = bid - 256;                   // 0..263
        p2_beta(e0, Z, HZ, c, Beta, smem);
        __syncthreads();
        p2_beta(e0 + 264, Z, HZ, c, Beta, smem);   // 264..527
    }
    grid.sync();

    // Phase 3: per-row t (blocks 0..255)
    if (bid < 256) p3_row(bid, u0, gamma, beta, targets, S, D, SD, smem);
    grid.sync();

    // Phase 4: per-row t (blocks 0..255); others exit
    if (bid < 256) p4_row(bid, Beta, D, SD, u0, S, gamma, beta, out, smem);
}

// ---- Fallback path: same phases as 4 ordinary launches (kernel boundary =
// barrier). Used only if hipLaunchCooperativeKernel is rejected.
__global__ __launch_bounds__(256) void fb1(
        const float* __restrict__ h, const float* __restrict__ U,
        const float* __restrict__ a, float* __restrict__ Z,
        float* __restrict__ HZ, float* __restrict__ c, float* __restrict__ S) {
    __shared__ __align__(16) float smem[2 * 8 * 516 + 256];
    int bid = blockIdx.x;
    if (bid < 256) p1_gemm8(bid, h, U, a, Z, HZ, c, smem);
    else           p1_scan(bid - 256, h, S, smem);
}
__global__ __launch_bounds__(256) void fb2(
        const float* __restrict__ Z, const float* __restrict__ W,
        const float* __restrict__ bb, const float* __restrict__ HZ,
        const float* __restrict__ c, float* __restrict__ u0,
        float* __restrict__ Beta) {
    __shared__ __align__(16) float smem[2 * 8 * 516 + 256];
    int bid = blockIdx.x;
    if (bid < 256) {
        p2_gemm8(bid, Z, W, bb, u0, smem);
    } else {
        int e0 = bid - 256;
        p2_beta(e0, Z, HZ, c, Beta, smem);
        __syncthreads();
        p2_beta(e0 + 264, Z, HZ, c, Beta, smem);
    }
}
__global__ __launch_bounds__(256) void fb3(
        const float* __restrict__ u0, const float* __restrict__ gamma,
        const float* __restrict__ beta, const int* __restrict__ targets,
        const float* __restrict__ S, float* __restrict__ D, float* __restrict__ SD) {
    __shared__ __align__(16) float smem[2 * 8 * 516 + 256];
    p3_row(blockIdx.x, u0, gamma, beta, targets, S, D, SD, smem);
}
__global__ __launch_bounds__(256) void fb4(
        const float* __restrict__ Beta, const float* __restrict__ D,
        const float* __restrict__ SD, const float* __restrict__ u0,
        const float* __restrict__ S, const float* __restrict__ gamma,
        const float* __restrict__ beta, float* __restrict__ out) {
    __shared__ __align__(16) float smem[2 * 8 * 516 + 256];
    p4_row(blockIdx.x, Beta, D, SD, u0, S, gamma, beta, out, smem);
}

extern "C" void kernel_launch(void* const* d_in, const int* in_sizes, int n_in,
                              void* d_out, int out_size, void* d_ws, size_t ws_size,
                              hipStream_t stream) {
    const float* h     = (const float*)d_in[0];
    const float* U     = (const float*)d_in[1];
    const float* W     = (const float*)d_in[2];
    const float* a     = (const float*)d_in[3];
    const float* bb    = (const float*)d_in[4];
    const float* gamma = (const float*)d_in[5];
    const float* beta  = (const float*)d_in[6];
    const int*   tgt   = (const int*)d_in[7];
    float* out = (float*)d_out;

    float* ws = (float*)d_ws;
    const int TH = T * H;
    float* Z    = ws;               // TH
    float* HZ   = Z    + TH;
    float* u0   = HZ   + TH;
    float* D    = u0   + TH;
    float* SD   = D    + TH;
    float* S    = SD   + TH;
    float* c    = S    + TH;        // T
    float* Beta = c    + T;         // T*T

    void* kargs[] = {
        (void*)&h, (void*)&U, (void*)&W, (void*)&a, (void*)&bb,
        (void*)&gamma, (void*)&beta, (void*)&tgt,
        (void*)&Z, (void*)&HZ, (void*)&c, (void*)&S,
        (void*)&u0, (void*)&D, (void*)&SD, (void*)&Beta, (void*)&out
    };
    hipError_t rc = hipLaunchCooperativeKernel((const void*)fused, dim3(520),
                                               dim3(256), kargs, 0, stream);
    if (rc != hipSuccess) {
        // Cooperative launch rejected (capture/occupancy): same phases as
        // 4 ordinary launches; kernel boundaries provide the barriers.
        fb1<<<264, 256, 0, stream>>>(h, U, a, Z, HZ, c, S);
        fb2<<<520, 256, 0, stream>>>(Z, W, bb, HZ, c, u0, Beta);
        fb3<<<T,   256, 0, stream>>>(u0, gamma, beta, tgt, S, D, SD);
        fb4<<<T,   256, 0, stream>>>(Beta, D, SD, u0, S, gamma, beta, out);
    }
}

// Round 7
// 112.847 us; speedup vs baseline: 2.7250x; 2.7250x over previous
//
#include <hip/hip_runtime.h>

#define T 256
#define H 512
#define EPSF 1e-5f

__device__ __forceinline__ float block_sum(float v, float* s4) {
    for (int o = 32; o; o >>= 1) v += __shfl_xor(v, o);
    int w = threadIdx.x >> 6;
    __syncthreads();
    if ((threadIdx.x & 63) == 0) s4[w] = v;
    __syncthreads();
    return s4[0] + s4[1] + s4[2] + s4[3];
}

__device__ __forceinline__ float block_max(float v, float* s4) {
    for (int o = 32; o; o >>= 1) v = fmaxf(v, __shfl_xor(v, o));
    int w = threadIdx.x >> 6;
    __syncthreads();
    if ((threadIdx.x & 63) == 0) s4[w] = v;
    __syncthreads();
    return fmaxf(fmaxf(s4[0], s4[1]), fmaxf(s4[2], s4[3]));
}

// 1024-thread block sum (16 waves)
__device__ __forceinline__ float bsum16(float v, float* s16) {
    for (int o = 32; o; o >>= 1) v += __shfl_xor(v, o);
    int w = threadIdx.x >> 6;
    __syncthreads();
    if ((threadIdx.x & 63) == 0) s16[w] = v;
    __syncthreads();
    float r = 0.f;
    #pragma unroll
    for (int i = 0; i < 16; ++i) r += s16[i];
    return r;
}

// bid 0..7: S-scan (two-pass, 64 cols/block, wave = 64-t chunk).
// bid 8..519: Z=relu(h@U+a), HZ=h.*Z, c. Tile 2t x 128q, K-split-4 across waves.
__global__ __launch_bounds__(256) void k1(
        const float* __restrict__ h, const float* __restrict__ U,
        const float* __restrict__ a, float* __restrict__ Z,
        float* __restrict__ HZ, float* __restrict__ c, float* __restrict__ S) {
    int bid = blockIdx.x, tid = threadIdx.x;
    int lane = tid & 63, w = tid >> 6;
    if (bid < 8) {
        __shared__ float csum[4][64];
        int q = bid * 64 + lane;
        int tbase = w * 64;
        float s = 0.f;
        for (int j = 0; j < 64; j += 8) {
            float v[8];
            #pragma unroll
            for (int u = 0; u < 8; ++u) v[u] = h[(tbase + j + u) * H + q];
            #pragma unroll
            for (int u = 0; u < 8; ++u) s += v[u];
        }
        csum[w][lane] = s;
        __syncthreads();
        float acc = 0.f;
        #pragma unroll
        for (int w2 = 0; w2 < 3; ++w2) if (w2 < w) acc += csum[w2][lane];
        for (int j = 0; j < 64; j += 8) {
            float v[8];
            #pragma unroll
            for (int u = 0; u < 8; ++u) v[u] = h[(tbase + j + u) * H + q];
            #pragma unroll
            for (int u = 0; u < 8; ++u) { acc += v[u]; S[(tbase + j + u) * H + q] = acc; }
        }
        return;
    }
    int b = bid - 8;
    int t0 = (b >> 2) * 2, qt = b & 3;
    __shared__ __align__(16) float sh[1024];
    __shared__ float2 part[3][2][64];
    ((float4*)sh)[tid] = ((const float4*)(h + t0 * H))[tid];
    __syncthreads();

    if (qt == 0 && w < 2) {
        float s = 0.f;
        #pragma unroll
        for (int j = 0; j < 8; ++j) s += sh[w * 512 + lane + j * 64];
        for (int o = 32; o; o >>= 1) s += __shfl_xor(s, o);
        if (lane == 0) c[t0 + w] = s;
    }

    int qc = qt * 64 + lane;
    const float2* U2 = (const float2*)U;
    float2 acc0 = {0.f, 0.f}, acc1 = {0.f, 0.f};
    int kbeg = w * 128;
    for (int k0 = kbeg; k0 < kbeg + 128; k0 += 8) {
        float2 bv[8];
        #pragma unroll
        for (int u = 0; u < 8; ++u) bv[u] = U2[(k0 + u) * 256 + qc];
        float a0[8], a1[8];
        #pragma unroll
        for (int u = 0; u < 8; ++u) { a0[u] = sh[k0 + u]; a1[u] = sh[512 + k0 + u]; }
        #pragma unroll
        for (int u = 0; u < 8; ++u) {
            acc0.x += a0[u] * bv[u].x; acc0.y += a0[u] * bv[u].y;
            acc1.x += a1[u] * bv[u].x; acc1.y += a1[u] * bv[u].y;
        }
    }
    if (w) { part[w - 1][0][lane] = acc0; part[w - 1][1][lane] = acc1; }
    __syncthreads();
    if (w == 0) {
        #pragma unroll
        for (int p = 0; p < 3; ++p) {
            acc0.x += part[p][0][lane].x; acc0.y += part[p][0][lane].y;
            acc1.x += part[p][1][lane].x; acc1.y += part[p][1][lane].y;
        }
        float2 av = ((const float2*)a)[qc];
        float z0x = fmaxf(acc0.x + av.x, 0.f), z0y = fmaxf(acc0.y + av.y, 0.f);
        float z1x = fmaxf(acc1.x + av.x, 0.f), z1y = fmaxf(acc1.y + av.y, 0.f);
        float2 h0 = ((float2*)sh)[qc], h1 = ((float2*)sh)[256 + qc];
        ((float2*)Z)[t0 * 256 + qc]        = make_float2(z0x, z0y);
        ((float2*)Z)[(t0 + 1) * 256 + qc]  = make_float2(z1x, z1y);
        ((float2*)HZ)[t0 * 256 + qc]       = make_float2(h0.x * z0x, h0.y * z0y);
        ((float2*)HZ)[(t0 + 1) * 256 + qc] = make_float2(h1.x * z1x, h1.y * z1y);
    }
}

// bid 0..511: u0 = Z@W + b (tile 2t x 128q, K-split-4).
// bid 512..1039: Beta = tril(Z@HZ^T,-1)+c, compact triangular 8x8 tiles.
__global__ __launch_bounds__(256) void k2(
        const float* __restrict__ Z, const float* __restrict__ W,
        const float* __restrict__ bb, const float* __restrict__ HZ,
        const float* __restrict__ c, float* __restrict__ u0,
        float* __restrict__ Beta) {
    __shared__ __align__(16) float smem[2 * 8 * 516 + 256];
    int bid = blockIdx.x, tid = threadIdx.x;
    int lane = tid & 63, w = tid >> 6;
    if (bid < 512) {
        float* sh = smem;
        float2* part = (float2*)(smem + 1024);
        int t0 = (bid >> 2) * 2, qt = bid & 3;
        ((float4*)sh)[tid] = ((const float4*)(Z + t0 * H))[tid];
        __syncthreads();
        int qc = qt * 64 + lane;
        const float2* W2 = (const float2*)W;
        float2 acc0 = {0.f, 0.f}, acc1 = {0.f, 0.f};
        int kbeg = w * 128;
        for (int k0 = kbeg; k0 < kbeg + 128; k0 += 8) {
            float2 bv[8];
            #pragma unroll
            for (int u = 0; u < 8; ++u) bv[u] = W2[(k0 + u) * 256 + qc];
            float a0[8], a1[8];
            #pragma unroll
            for (int u = 0; u < 8; ++u) { a0[u] = sh[k0 + u]; a1[u] = sh[512 + k0 + u]; }
            #pragma unroll
            for (int u = 0; u < 8; ++u) {
                acc0.x += a0[u] * bv[u].x; acc0.y += a0[u] * bv[u].y;
                acc1.x += a1[u] * bv[u].x; acc1.y += a1[u] * bv[u].y;
            }
        }
        if (w) { part[((w - 1) * 2 + 0) * 64 + lane] = acc0; part[((w - 1) * 2 + 1) * 64 + lane] = acc1; }
        __syncthreads();
        if (w == 0) {
            #pragma unroll
            for (int p = 0; p < 3; ++p) {
                float2 p0 = part[(p * 2 + 0) * 64 + lane];
                float2 p1 = part[(p * 2 + 1) * 64 + lane];
                acc0.x += p0.x; acc0.y += p0.y;
                acc1.x += p1.x; acc1.y += p1.y;
            }
            float2 bv = ((const float2*)bb)[qc];
            ((float2*)u0)[t0 * 256 + qc]       = make_float2(acc0.x + bv.x, acc0.y + bv.y);
            ((float2*)u0)[(t0 + 1) * 256 + qc] = make_float2(acc1.x + bv.x, acc1.y + bv.y);
        }
    } else {
        int e = bid - 512;                         // 0..527 compact triangular
        int ti = (int)((sqrtf(8.f * (float)e + 1.f) - 1.f) * 0.5f);
        while ((ti + 1) * (ti + 2) / 2 <= e) ++ti;
        while (ti * (ti + 1) / 2 > e) --ti;
        int ii = e - ti * (ti + 1) / 2;
        int t0 = ti * 8, i0 = ii * 8;
        float* Zs = smem;                 // [8][516]
        float* Hs = smem + 8 * 516;       // [8][516]
        float* red = smem + 2 * 8 * 516;  // [4][64]
        #pragma unroll
        for (int j = 0; j < 4; ++j) {
            int idx = tid + j * 256;
            int row = idx >> 7, col4 = idx & 127;
            float4 v = ((const float4*)(Z + (t0 + row) * H))[col4];
            *(float4*)&Zs[row * 516 + col4 * 4] = v;
            float4 g = ((const float4*)(HZ + (i0 + row) * H))[col4];
            *(float4*)&Hs[row * 516 + col4 * 4] = g;
        }
        __syncthreads();
        int ks = tid >> 6, r = (tid >> 3) & 7, ci = tid & 7;
        float acc = 0.f;
        int kb = ks * 128;
        #pragma unroll 4
        for (int k0 = kb; k0 < kb + 128; k0 += 8) {
            float4 z0 = *(float4*)&Zs[r * 516 + k0];
            float4 z1 = *(float4*)&Zs[r * 516 + k0 + 4];
            float4 h0 = *(float4*)&Hs[ci * 516 + k0];
            float4 h1 = *(float4*)&Hs[ci * 516 + k0 + 4];
            acc += z0.x * h0.x + z0.y * h0.y + z0.z * h0.z + z0.w * h0.w
                 + z1.x * h1.x + z1.y * h1.y + z1.z * h1.z + z1.w * h1.w;
        }
        red[ks * 64 + r * 8 + ci] = acc;
        __syncthreads();
        if (tid < 64) {
            int r2 = tid >> 3, c2 = tid & 7;
            float v = red[tid] + red[64 + tid] + red[128 + tid] + red[192 + tid];
            int t = t0 + r2, i = i0 + c2;
            Beta[t * 256 + i] = (i < t) ? v + c[i] : 0.f;
        }
    }
}

// Per-row t: y=LN(u0), g=softmax(y)-onehot, D=LN-backward(g), SD=S.*D
__global__ __launch_bounds__(256) void k3(
        const float* __restrict__ u0, const float* __restrict__ gamma,
        const float* __restrict__ beta, const int* __restrict__ targets,
        const float* __restrict__ S, float* __restrict__ D, float* __restrict__ SD) {
    __shared__ float s4[4];
    int t = blockIdx.x, tid = threadIdx.x;
    float2 uv = ((const float2*)u0)[t * 256 + tid];
    float2 gv = ((const float2*)gamma)[tid];
    float2 bv = ((const float2*)beta)[tid];

    float m = block_sum(uv.x + uv.y, s4) * (1.f / H);
    float d0 = uv.x - m, d1 = uv.y - m;
    float var = block_sum(d0 * d0 + d1 * d1, s4) * (1.f / H);
    float s = rsqrtf(var + EPSF);
    float xh0 = d0 * s, xh1 = d1 * s;
    float y0 = xh0 * gv.x + bv.x;
    float y1 = xh1 * gv.y + bv.y;

    float ymax = block_max(fmaxf(y0, y1), s4);
    float e0 = __expf(y0 - ymax), e1 = __expf(y1 - ymax);
    float Zs = block_sum(e0 + e1, s4);
    float invZ = 1.f / Zs;
    int tgt = targets[t];
    float g0 = e0 * invZ - (2 * tid == tgt ? 1.f : 0.f);
    float g1 = e1 * invZ - (2 * tid + 1 == tgt ? 1.f : 0.f);
    float gy0 = g0 * gv.x, gy1 = g1 * gv.y;

    float mgy = block_sum(gy0 + gy1, s4) * (1.f / H);
    float mgx = block_sum(gy0 * xh0 + gy1 * xh1, s4) * (1.f / H);

    float dd0 = s * (gy0 - mgy - xh0 * mgx);
    float dd1 = s * (gy1 - mgy - xh1 * mgx);
    float2 sv = ((const float2*)S)[t * 256 + tid];
    ((float2*)D)[t * 256 + tid]  = make_float2(dd0, dd1);
    ((float2*)SD)[t * 256 + tid] = make_float2(sv.x * dd0, sv.y * dd1);
}

// One block (1024 thr) per row t: 4 i-groups x 256 col-lanes compute
// A1 = Beta_t@D, A2 = Beta_t@SD; LDS-reduce; pre = u0 - S_t.*A1 + A2; out = LN(pre).
__global__ __launch_bounds__(1024) void k4(
        const float* __restrict__ Beta, const float* __restrict__ D,
        const float* __restrict__ SD, const float* __restrict__ u0,
        const float* __restrict__ S, const float* __restrict__ gamma,
        const float* __restrict__ beta, float* __restrict__ out) {
    __shared__ float Brow[256];
    __shared__ float r1[4][512];
    __shared__ float r2[4][512];
    __shared__ float s16[16];
    int t = blockIdx.x, tid = threadIdx.x;
    if (tid < 256) Brow[tid] = Beta[t * 256 + tid];
    __syncthreads();

    int ig = tid >> 8, qc = tid & 255;
    int ibeg = ig * 64;
    int iend = min((t + 7) & ~7, ibeg + 64);
    float2 a1 = {0.f, 0.f}, a2 = {0.f, 0.f};
    const float2* D2 = (const float2*)D;
    const float2* SD2 = (const float2*)SD;
    for (int k0 = ibeg; k0 < iend; k0 += 8) {
        float2 dv[8], sv[8];
        #pragma unroll
        for (int u = 0; u < 8; ++u) {
            dv[u] = D2[(k0 + u) * 256 + qc];
            sv[u] = SD2[(k0 + u) * 256 + qc];
        }
        #pragma unroll
        for (int u = 0; u < 8; ++u) {
            float bw = Brow[k0 + u];
            a1.x += bw * dv[u].x; a1.y += bw * dv[u].y;
            a2.x += bw * sv[u].x; a2.y += bw * sv[u].y;
        }
    }
    r1[ig][2 * qc] = a1.x; r1[ig][2 * qc + 1] = a1.y;
    r2[ig][2 * qc] = a2.x; r2[ig][2 * qc + 1] = a2.y;
    __syncthreads();

    float p = 0.f;
    if (tid < 512) {
        float A1 = r1[0][tid] + r1[1][tid] + r1[2][tid] + r1[3][tid];
        float A2 = r2[0][tid] + r2[1][tid] + r2[2][tid] + r2[3][tid];
        p = u0[t * H + tid] - S[t * H + tid] * A1 + A2;
    }
    float m = bsum16(p, s16) * (1.f / H);
    float d = (tid < 512) ? p - m : 0.f;
    float var = bsum16(d * d, s16) * (1.f / H);
    float s = rsqrtf(var + EPSF);
    if (tid < 512)
        out[t * H + tid] = d * s * gamma[tid] + beta[tid];
}

extern "C" void kernel_launch(void* const* d_in, const int* in_sizes, int n_in,
                              void* d_out, int out_size, void* d_ws, size_t ws_size,
                              hipStream_t stream) {
    const float* h     = (const float*)d_in[0];
    const float* U     = (const float*)d_in[1];
    const float* W     = (const float*)d_in[2];
    const float* a     = (const float*)d_in[3];
    const float* b     = (const float*)d_in[4];
    const float* gamma = (const float*)d_in[5];
    const float* beta  = (const float*)d_in[6];
    const int*   tgt   = (const int*)d_in[7];
    float* out = (float*)d_out;

    float* ws = (float*)d_ws;
    const int TH = T * H;
    float* Z    = ws;               // TH
    float* HZ   = Z    + TH;
    float* u0   = HZ   + TH;
    float* D    = u0   + TH;
    float* SD   = D    + TH;
    float* S    = SD   + TH;
    float* c    = S    + TH;        // T
    float* Beta = c    + T;         // T*T

    k1<<<520,  256, 0, stream>>>(h, U, a, Z, HZ, c, S);
    k2<<<1040, 256, 0, stream>>>(Z, W, b, HZ, c, u0, Beta);
    k3<<<T,    256, 0, stream>>>(u0, gamma, beta, tgt, S, D, SD);
    k4<<<T,   1024, 0, stream>>>(Beta, D, SD, u0, S, gamma, beta, out);
}